// Round 15
// baseline (43.269 us; speedup 1.0000x reference)
//
#include <hip/hip_runtime.h>

#define TT 32     // tags
#define LL 16     // max span length
#define BURN 16   // burn-in steps (validated r11/r14: absmax 0.0)
#define KCH 16    // chunk payload length (steps)

// broadcast lane p's value to all lanes (VALU readlane, no LDS pipe)
#if __has_builtin(__builtin_amdgcn_readlane)
#define RLF(U, P) __uint_as_float(__builtin_amdgcn_readlane((U), (P)))
#else
#define RLF(U, P) __uint_as_float(__shfl((int)(U), (P)))
#endif

// ---------------------------------------------------------------------------
// Chunk-parallel scan, readlane-MVM, 2 waves/SIMD edition.
// Chunk c covers payload [c*16,(c+1)*16); gstart = max(0, c*16-16); c>=2
// burns in 16 steps from an all-ones state (projective contraction; absmax
// 0.0 validated at BURN=16). c=0,1 are exact-from-0.
// Per lane: tag t = lane&31 (halves duplicate), FULL 32-wide Trx row; after
// the dot every lane holds the complete S_t, so the next step's MVM is 32x
// v_readlane + 32 fma -- zero LDS on the recurrence. Emissions: 4-step
// groups staged float2/lane, exp applied at stage time, double-buffered
// 8KB rings (16KB total -> 8 blocks/CU = 2 waves/SIMD).
// Each chunk reports m_end - m_pre of m(x)=log(sum_t H[t]); chunk whose
// window starts at 0 with nb==1 reports absolute m_end; last chunk adds the
// terminal correction; ws2 telescopes.
// ---------------------------------------------------------------------------
__launch_bounds__(64, 2)
__global__ void semicrf_rl2_kernel(const float* __restrict__ feats,
                                   const float* __restrict__ trans,
                                   const float* __restrict__ tbound,
                                   const float* __restrict__ w1p,
                                   const float* __restrict__ w2p,
                                   float* __restrict__ ws2,
                                   int S, int C, int swz) {
    __shared__ __align__(16) float ring0[16 * 128];  // 16 planes x 4 steps x 32 t
    __shared__ __align__(16) float ring1[16 * 128];
    int c = (int)blockIdx.x;
    if (swz) c = (c & 7) * (C >> 3) + (c >> 3);      // XCD-contiguous chunks
    const int lane = (int)threadIdx.x;
    const int t = lane & 31;
    const float w1 = w1p[0];
    const float w2 = w2p[0];
    const int Sm1 = S - 1;
    const int lane2 = lane * 2;

    int gstart = c * KCH - BURN;
    if (gstart < 0) gstart = 0;
    const bool exact = (gstart == 0);
    const int nb = ((c + 1) * KCH - gstart) >> 4;    // 16-step blocks
    const int preb = (c * KCH - gstart) >> 4;        // m_pre capture block

    // full Trx row for this lane's tag (32 regs)
    float trx[32];
#pragma unroll
    for (int i = 0; i < 32; ++i)
        trx[i] = __expf(w1 * trans[t * TT + i]);
    float trxsum = 0.0f;
#pragma unroll
    for (int i = 0; i < 32; ++i) trxsum += trx[i];

    float D[16];
#pragma unroll
    for (int k = 0; k < 16; ++k) D[k] = exact ? 0.0f : trxsum;

    float etb0 = __expf(w1 * tbound[t]);
    float bem[16];
#pragma unroll
    for (int j = 0; j < 16; ++j) bem[j] = 0.0f;
    if (exact) {
#pragma unroll
        for (int j = 0; j < 16; ++j)                 // bemit[j] = feats[j][0][t]
            bem[j] = __expf(w2 * feats[(size_t)j * (size_t)S * 32u + (size_t)t]);
    }

    float mref = 0.0f, Svk = 1.0f, inv = 1.0f;
    float Svp = 1.0f;                // prev step's full S_t (ones init for burn-in)
    int s0 = gstart;
    float2 gst[16];                                  // staged raw: next 4 steps

// issue 16 float2 loads: 4-step strip per plane at s0+OFF
#define LOADG(OFF)                                                            \
    {                                                                         \
        int gs_ = s0 + (OFF); if (gs_ > S - 4) gs_ = S - 4;                   \
        _Pragma("unroll")                                                     \
        for (int l = 0; l < 16; ++l)                                          \
            gst[l] = *(const float2*)(feats +                                 \
                ((size_t)l * (size_t)Sm1 + (size_t)gs_) * 32 + lane2);        \
    }

// exp the staged regs and write to ring buffer P, then load s0+OFF
#define GROUPOPS(P, OFF)                                                      \
    {                                                                         \
        float* rw_ = (P) ? ring1 : ring0;                                     \
        _Pragma("unroll")                                                     \
        for (int l = 0; l < 16; ++l) {                                        \
            float2 e_;                                                        \
            e_.x = __expf(w2 * gst[l].x);                                     \
            e_.y = __expf(w2 * gst[l].y);                                     \
            *(float2*)&rw_[l * 128 + lane2] = e_;                             \
        }                                                                     \
        LOADG(OFF)                                                            \
    }

#define SCRF_STEP(J, IS_B0, IS_FIRST, SCALED)                                 \
    {                                                                         \
        const int j_ = (J);                                                   \
        const float* rb_ = ((j_ >> 2) & 1) ? ring1 : ring0;                   \
        /* 16 pre-exp'd emissions (bank = t, broadcast across halves) */      \
        float ew_[16];                                                        \
        _Pragma("unroll")                                                     \
        for (int l = 0; l < 16; ++l)                                          \
            ew_[l] = rb_[l * 128 + (j_ & 3) * 32 + t];                        \
        /* MVM via 32x readlane of prev S (no LDS on the chain) */            \
        float Dn_;                                                            \
        if (IS_FIRST) {                                                       \
            Dn_ = 0.0f;                                                       \
        } else {                                                              \
            unsigned svu_ = __float_as_uint(Svp);                             \
            float ac_[4] = {0.f, 0.f, 0.f, 0.f};                              \
            _Pragma("unroll")                                                 \
            for (int p = 0; p < 32; ++p)                                      \
                ac_[p & 3] = fmaf(trx[p], RLF(svu_, p), ac_[p & 3]);          \
            float dh_ = (ac_[0] + ac_[1]) + (ac_[2] + ac_[3]);                \
            Dn_ = (SCALED) ? dh_ * inv : dh_;                                 \
            D[(j_ - 1) & 15] = Dn_;                                           \
        }                                                                     \
        float q0_ = D[(j_ - 2) & 15] * ew_[1];                                \
        float q1_ = D[(j_ - 3) & 15] * ew_[2];                                \
        float q2_ = D[(j_ - 4) & 15] * ew_[3];                                \
        float q3_ = D[(j_ - 5) & 15] * ew_[4];                                \
        q0_ = fmaf(D[(j_ - 6) & 15], ew_[5], q0_);                            \
        q1_ = fmaf(D[(j_ - 7) & 15], ew_[6], q1_);                            \
        q2_ = fmaf(D[(j_ - 8) & 15], ew_[7], q2_);                            \
        q3_ = fmaf(D[(j_ - 9) & 15], ew_[8], q3_);                            \
        q0_ = fmaf(D[(j_ - 10) & 15], ew_[9], q0_);                           \
        q1_ = fmaf(D[(j_ - 11) & 15], ew_[10], q1_);                          \
        q2_ = fmaf(D[(j_ - 12) & 15], ew_[11], q2_);                          \
        q3_ = fmaf(D[(j_ - 13) & 15], ew_[12], q3_);                          \
        q0_ = fmaf(D[(j_ - 14) & 15], ew_[13], q0_);                          \
        q1_ = fmaf(D[(j_ - 15) & 15], ew_[14], q1_);                          \
        q2_ = fmaf(D[(j_ - 16) & 15], ew_[15], q2_);                          \
        float p15_ = (q0_ + q1_) + (q2_ + q3_);                               \
        p15_ = (t == 0) ? 0.0f : p15_;     /* O-tag: span len 1 only */       \
        float Sv_ = fmaf(Dn_, ew_[0], p15_);                                  \
        if (IS_B0) {                                                          \
            float bt_ = etb0 * bem[j_];                                       \
            if (j_ > 0) bt_ = (t == 0) ? 0.0f : bt_;                          \
            Sv_ += bt_;                                                       \
        }                                                                     \
        Svp = Sv_;                                                            \
        Svk = Sv_;                                                            \
    }

// one 16-step block = 4 groups of 4 (r10-proven parity schedule).
// Entry invariant: ring0 = s0..s0+3, gst = s0+4..7 (raw).
#define BLOCK16(B0, FIRST, SCALED)                                            \
    SCRF_STEP(0, B0, FIRST, SCALED)                                           \
    SCRF_STEP(1, B0, false, false)                                            \
    SCRF_STEP(2, B0, false, false)                                            \
    SCRF_STEP(3, B0, false, false)                                            \
    GROUPOPS(1, 8)                                                            \
    SCRF_STEP(4, B0, false, false)                                            \
    SCRF_STEP(5, B0, false, false)                                            \
    SCRF_STEP(6, B0, false, false)                                            \
    SCRF_STEP(7, B0, false, false)                                            \
    GROUPOPS(0, 12)                                                           \
    SCRF_STEP(8, B0, false, false)                                            \
    SCRF_STEP(9, B0, false, false)                                            \
    SCRF_STEP(10, B0, false, false)                                           \
    SCRF_STEP(11, B0, false, false)                                           \
    GROUPOPS(1, 16)                                                           \
    SCRF_STEP(12, B0, false, false)                                           \
    SCRF_STEP(13, B0, false, false)                                           \
    SCRF_STEP(14, B0, false, false)                                           \
    SCRF_STEP(15, B0, false, false)                                           \
    GROUPOPS(0, 20)

    // ---- prologue: group 0 -> ring0 (exp'd), stage group 1 ----
    LOADG(0)
    {
#pragma unroll
        for (int l = 0; l < 16; ++l) {
            float2 e_;
            e_.x = __expf(w2 * gst[l].x);
            e_.y = __expf(w2 * gst[l].y);
            *(float2*)&ring0[l * 128 + lane2] = e_;
        }
    }
    LOADG(4)

    // ---- block 0 ----
    if (exact) {
        BLOCK16(true, true, false)
    } else {
        BLOCK16(false, false, false)
    }

    // ---- remaining blocks ----
    float m_pre = 0.0f;
    for (int b = 1; b < nb; ++b) {
        s0 += 16;
        if (b == preb) {   // capture m at global step c*K-1 (pre-rescale)
            float sv = Svk;
#pragma unroll
            for (int m = 1; m <= 16; m <<= 1) sv += __shfl_xor(sv, m);
            m_pre = mref + __logf(sv);
        }
        // re-anchor: divide history by max_t(Sv_last), recenter to e^-20
        float mx = Svk;
#pragma unroll
        for (int m = 1; m <= 16; m <<= 1)
            mx = fmaxf(mx, __shfl_xor(mx, m));
        inv = 2.0611536e-09f / mx;          // e^-20 / mx
        mref += __logf(mx) + 20.0f;
#pragma unroll
        for (int k = 0; k < 16; ++k) D[k] *= inv;

        BLOCK16(false, false, true)         // pending Svp's MVM gets *inv
    }
#undef BLOCK16
#undef SCRF_STEP
#undef GROUPOPS
#undef LOADG

    // ---- chunk outputs ----
    float se = Svk;
#pragma unroll
    for (int m = 1; m <= 16; m <<= 1) se += __shfl_xor(se, m);
    float m_end = mref + __logf(se);
    float contrib = (preb == 0) ? m_end : (m_end - m_pre);
    if (lane == 0) ws2[c] = contrib;
    if (c == C - 1) {
        float etb1 = __expf(w1 * tbound[TT + t]);
        float sc = Svk * etb1;
#pragma unroll
        for (int m = 1; m <= 16; m <<= 1) sc += __shfl_xor(sc, m);
        if (lane == 0) ws2[C] = __logf(sc) - __logf(se);
    }
}

// ---------------------------------------------------------------------------
// Ordered reduction of the C+1 chunk contributions.
// ---------------------------------------------------------------------------
__global__ void stitch_kernel(const float* __restrict__ ws2,
                              float* __restrict__ out, int n) {
    const int lane = (int)threadIdx.x;
    float v = 0.0f;
    for (int i = lane; i < n; i += 64) v += ws2[i];
#pragma unroll
    for (int m = 1; m <= 32; m <<= 1) v += __shfl_xor(v, m);
    if (lane == 0) out[0] = v;
}

// ---------------------------------------------------------------------------
// Fallback (S not a multiple of 32 / tiny ws): proven round-2 kernel.
// ---------------------------------------------------------------------------
__launch_bounds__(64, 1)
__global__ void semicrf_scan_fb_kernel(const float* __restrict__ src,
                                       const float* __restrict__ trans,
                                       const float* __restrict__ tbound,
                                       const float* __restrict__ w1p,
                                       const float* __restrict__ w2p,
                                       float* __restrict__ out, int S) {
    __shared__ float4 ldsS4[8];
    const int lane = threadIdx.x;
    const int t = lane & 31;
    const int h = lane >> 5;
    const float w1 = w1p[0];
    const float w2 = w2p[0];
    const unsigned toff = (unsigned)t * 4u;
    const unsigned planeB = (unsigned)S * 128u;
    const size_t planeE = (size_t)S * TT;

    float trx[16];
#pragma unroll
    for (int i = 0; i < 16; ++i)
        trx[i] = __expf(w1 * trans[t * TT + h * 16 + i]);

    float D[16];
#pragma unroll
    for (int k = 0; k < 16; ++k) D[k] = 0.0f;

    unsigned off[16];
#pragma unroll
    for (int k = 0; k < 16; ++k) {
        int l = (-1 - k) & 15;
        int c = 0 - l; if (c < 0) c = 0;
        off[k] = (unsigned)(l * S + c) * 128u + toff;
    }

    float ring[4][16];
#pragma unroll
    for (int st = 0; st < 4; ++st) {
#pragma unroll
        for (int k = 0; k < 16; ++k)
            ring[st][k] = *(const float*)((const char*)src + off[k]);
        const int qr = st & 15;
        unsigned c = (unsigned)((st + 1 <= S - 1) ? st + 1 : S - 1);
#pragma unroll
        for (int k = 0; k < 16; ++k)
            off[k] = (k == qr) ? (c * 128u + toff) : (off[k] + planeB);
    }

    float etb0 = __expf(w1 * tbound[t]);
    float bem[16];
#pragma unroll
    for (int j = 0; j < 16; ++j)
        bem[j] = __expf(w2 * src[(size_t)j * planeE + (size_t)t]);

    float mref = 0.0f;
    float Svk = 1.0f;

#define FB_STEP(J, S0V, IS_B0)                                                \
    {                                                                         \
        const int j_ = (J);                                                   \
        float ewv[16];                                                        \
        _Pragma("unroll")                                                     \
        for (int k = 0; k < 16; ++k)                                          \
            ewv[k] = __expf(w2 * ring[j_ & 3][k]);                            \
        float p0 = 0.f, p1 = 0.f, p2 = 0.f, p3 = 0.f;                         \
        _Pragma("unroll")                                                     \
        for (int k = 0; k < 16; k += 4) {                                     \
            p0 = fmaf(D[k + 0], ewv[k + 0], p0);                              \
            p1 = fmaf(D[k + 1], ewv[k + 1], p1);                              \
            p2 = fmaf(D[k + 2], ewv[k + 2], p2);                              \
            p3 = fmaf(D[k + 3], ewv[k + 3], p3);                              \
        }                                                                     \
        float part = (p0 + p1) + (p2 + p3);                                   \
        {                                                                     \
            const int kp = (j_ - 1) & 15;                                     \
            float alt = D[kp] * ewv[kp];                                      \
            part = (t == 0) ? alt : part;                                     \
        }                                                                     \
        _Pragma("unroll")                                                     \
        for (int k = 0; k < 16; ++k)                                          \
            ring[(j_ + 4) & 3][k] =                                           \
                *(const float*)((const char*)src + off[k]);                   \
        {                                                                     \
            const int qr = (j_ + 4) & 15;                                     \
            long T1 = (long)(S0V) + j_ + 4 + 1;                               \
            unsigned c_ = (unsigned)(T1 <= (long)(S - 1) ? T1 : (long)(S - 1)); \
            _Pragma("unroll")                                                 \
            for (int k = 0; k < 16; ++k)                                      \
                off[k] = (k == qr) ? (c_ * 128u + toff) : (off[k] + planeB);  \
        }                                                                     \
        float Sv = part + __shfl_xor(part, 32);                               \
        if (IS_B0) {                                                          \
            float bt = etb0 * bem[j_];                                        \
            if (j_ > 0) bt = (t == 0) ? 0.0f : bt;                            \
            Sv += bt;                                                         \
        }                                                                     \
        ((float*)ldsS4)[t] = Sv;                                              \
        __syncthreads();                                                      \
        float4 a0 = ldsS4[h * 4 + 0];                                         \
        float4 a1 = ldsS4[h * 4 + 1];                                         \
        float4 a2 = ldsS4[h * 4 + 2];                                         \
        float4 a3 = ldsS4[h * 4 + 3];                                         \
        float dn0 = fmaf(trx[0],  a0.x, fmaf(trx[1],  a0.y,                   \
                    fmaf(trx[2],  a0.z, trx[3]  * a0.w)));                    \
        float dn1 = fmaf(trx[4],  a1.x, fmaf(trx[5],  a1.y,                   \
                    fmaf(trx[6],  a1.z, trx[7]  * a1.w)));                    \
        float dn2 = fmaf(trx[8],  a2.x, fmaf(trx[9],  a2.y,                   \
                    fmaf(trx[10], a2.z, trx[11] * a2.w)));                    \
        float dn3 = fmaf(trx[12], a3.x, fmaf(trx[13], a3.y,                   \
                    fmaf(trx[14], a3.z, trx[15] * a3.w)));                    \
        D[j_] = (dn0 + dn1) + (dn2 + dn3);                                    \
        Svk = Sv;                                                             \
    }

#pragma unroll
    for (int j = 0; j < 16; ++j) {
        FB_STEP(j, 0L, true)
    }
    const int nblocks = S / 16;
    long s0 = 16;
    for (int b = 1; b < nblocks; ++b) {
        float mx = Svk;
#pragma unroll
        for (int m = 1; m <= 16; m <<= 1)
            mx = fmaxf(mx, __shfl_xor(mx, m));
        float invv = 2.0611536e-09f / mx;
        mref += __logf(mx) + 20.0f;
#pragma unroll
        for (int k = 0; k < 16; ++k) D[k] *= invv;
#pragma unroll
        for (int j = 0; j < 16; ++j) {
            FB_STEP(j, s0, false)
        }
        s0 += 16;
    }
#undef FB_STEP

    float etb1 = __expf(w1 * tbound[TT + t]);
    float val = Svk * etb1;
#pragma unroll
    for (int m = 1; m <= 16; m <<= 1) val += __shfl_xor(val, m);
    if (lane == 0) out[0] = mref + __logf(val);
}

// ---------------------------------------------------------------------------
extern "C" void kernel_launch(void* const* d_in, const int* in_sizes, int n_in,
                              void* d_out, int out_size, void* d_ws, size_t ws_size,
                              hipStream_t stream) {
    const float* feats = (const float*)d_in[0];   // [L=16, S, T=32]
    const float* trans = (const float*)d_in[1];   // [T, T]
    const float* tb    = (const float*)d_in[2];   // [2, T]
    const float* w1    = (const float*)d_in[3];
    const float* w2    = (const float*)d_in[4];
    float* out = (float*)d_out;

    const int n = in_sizes[0];            // L*S*T
    const int S = n / (LL * TT);

    // K=16 chunks (BURN=16): need S % 32 == 0 (payload+burn windows align).
    int C = 0;
    if ((S & 31) == 0 && S >= 64) C = S >> 4;
    const int swz = (C > 0 && (C & 7) == 0) ? 1 : 0;

    const size_t need = (size_t)(C + 2) * sizeof(float);
    if (C > 1 && ws_size >= need) {
        float* ws2 = (float*)d_ws;
        semicrf_rl2_kernel<<<C, 64, 0, stream>>>(feats, trans, tb, w1, w2,
                                                 ws2, S, C, swz);
        stitch_kernel<<<1, 64, 0, stream>>>(ws2, out, C + 1);
    } else {
        semicrf_scan_fb_kernel<<<1, 64, 0, stream>>>(feats, trans, tb, w1, w2, out, S);
    }
}

// Round 16
// 36.972 us; speedup vs baseline: 1.1703x; 1.1703x over previous
//
#include <hip/hip_runtime.h>

#define TT 32     // tags
#define LL 16     // max span length
#define BURN 16   // burn-in steps (validated r11/r14: absmax 0.0)
#define KCH 64    // chunk payload length (steps): 1.25x read duplication

// broadcast lane p's value to all lanes (VALU readlane, no LDS pipe)
#if __has_builtin(__builtin_amdgcn_readlane)
#define RLF(U, P) __uint_as_float(__builtin_amdgcn_readlane((U), (P)))
#else
#define RLF(U, P) __uint_as_float(__shfl((int)(U), (P)))
#endif

// ---------------------------------------------------------------------------
// Chunk-parallel scan, readlane-MVM (r14 structure, K=64).
// Chunk c covers payload [c*64,(c+1)*64); gstart = max(0, c*64-16); c>0 burns
// in 16 steps from an all-ones state (projective contraction; absmax 0.0
// validated at BURN=16). Per lane: tag t = lane&31 (halves duplicate), FULL
// 32-wide Trx row; after the dot every lane holds the complete S_t, so the
// next step's MVM is 32x v_readlane + 32 fma -- zero LDS on the recurrence.
// Emissions: 8-step groups staged float4/lane (1KB contiguous per plane),
// exp applied at stage time, double-buffered 16KB rings.
// Each chunk reports m_end - m_pre of m(x)=log(sum_t H[t]); chunk whose
// window starts at 0 reports absolute m_end; last chunk adds the terminal
// correction; ws2 telescopes.
// ---------------------------------------------------------------------------
__launch_bounds__(64, 1)
__global__ void semicrf_rl_kernel(const float* __restrict__ feats,
                                  const float* __restrict__ trans,
                                  const float* __restrict__ tbound,
                                  const float* __restrict__ w1p,
                                  const float* __restrict__ w2p,
                                  float* __restrict__ ws2,
                                  int S, int C, int swz) {
    __shared__ __align__(16) float ring0[16 * 256];  // 16 planes x 8 steps x 32 t
    __shared__ __align__(16) float ring1[16 * 256];
    int c = (int)blockIdx.x;
    if (swz) c = (c & 7) * (C >> 3) + (c >> 3);      // XCD-contiguous chunks
    const int lane = (int)threadIdx.x;
    const int t = lane & 31;
    const float w1 = w1p[0];
    const float w2 = w2p[0];
    const int Sm1 = S - 1;

    int gstart = c * KCH - BURN;
    if (gstart < 0) gstart = 0;
    const bool exact = (gstart == 0);
    const int nb = ((c + 1) * KCH - gstart) >> 4;    // 16-step blocks
    const int preb = (c * KCH - gstart) >> 4;        // m_pre capture block

    // full Trx row for this lane's tag (32 regs)
    float trx[32];
#pragma unroll
    for (int i = 0; i < 32; ++i)
        trx[i] = __expf(w1 * trans[t * TT + i]);
    float trxsum = 0.0f;
#pragma unroll
    for (int i = 0; i < 32; ++i) trxsum += trx[i];

    float D[16];
#pragma unroll
    for (int k = 0; k < 16; ++k) D[k] = exact ? 0.0f : trxsum;

    float etb0 = __expf(w1 * tbound[t]);
    float bem[16];
#pragma unroll
    for (int j = 0; j < 16; ++j) bem[j] = 0.0f;
    if (exact) {
#pragma unroll
        for (int j = 0; j < 16; ++j)                 // bemit[j] = feats[j][0][t]
            bem[j] = __expf(w2 * feats[(size_t)j * (size_t)S * 32u + (size_t)t]);
    }

    float mref = 0.0f, Svk = 1.0f, inv = 1.0f;
    float Svp = 1.0f;                // prev step's full S_t (ones init)
    int s0 = gstart;
    float4 gst[16];                                  // staged raw: next 8 steps

// issue 16 float4 loads: 8-step strip (1KB contiguous) per plane at s0+OFF
#define LOADG(OFF)                                                            \
    {                                                                         \
        int gs_ = s0 + (OFF); if (gs_ > S - 8) gs_ = S - 8;                   \
        _Pragma("unroll")                                                     \
        for (int l = 0; l < 16; ++l)                                          \
            gst[l] = *(const float4*)(feats +                                 \
                ((size_t)l * (size_t)Sm1 + (size_t)gs_) * 32 + lane * 4);     \
    }

// exp the staged regs and write to ring buffer P, then load s0+OFF
#define GROUPOPS(P, OFF)                                                      \
    {                                                                         \
        float* rw_ = (P) ? ring1 : ring0;                                     \
        _Pragma("unroll")                                                     \
        for (int l = 0; l < 16; ++l) {                                        \
            float4 e_;                                                        \
            e_.x = __expf(w2 * gst[l].x);                                     \
            e_.y = __expf(w2 * gst[l].y);                                     \
            e_.z = __expf(w2 * gst[l].z);                                     \
            e_.w = __expf(w2 * gst[l].w);                                     \
            *(float4*)&rw_[l * 256 + lane * 4] = e_;                          \
        }                                                                     \
        LOADG(OFF)                                                            \
    }

#define SCRF_STEP(J, IS_B0, IS_FIRST, SCALED)                                 \
    {                                                                         \
        const int j_ = (J);                                                   \
        const float* rb_ = (j_ >= 8) ? ring1 : ring0;                         \
        /* 16 pre-exp'd emissions (bank = t, broadcast across halves) */      \
        float ew_[16];                                                        \
        _Pragma("unroll")                                                     \
        for (int l = 0; l < 16; ++l)                                          \
            ew_[l] = rb_[l * 256 + (j_ & 7) * 32 + t];                        \
        /* MVM via 32x readlane of prev S (no LDS on the chain) */            \
        float Dn_;                                                            \
        if (IS_FIRST) {                                                       \
            Dn_ = 0.0f;                                                       \
        } else {                                                              \
            unsigned svu_ = __float_as_uint(Svp);                             \
            float ac_[4] = {0.f, 0.f, 0.f, 0.f};                              \
            _Pragma("unroll")                                                 \
            for (int p = 0; p < 32; ++p)                                      \
                ac_[p & 3] = fmaf(trx[p], RLF(svu_, p), ac_[p & 3]);          \
            float dh_ = (ac_[0] + ac_[1]) + (ac_[2] + ac_[3]);                \
            Dn_ = (SCALED) ? dh_ * inv : dh_;                                 \
            D[(j_ - 1) & 15] = Dn_;                                           \
        }                                                                     \
        float q0_ = D[(j_ - 2) & 15] * ew_[1];                                \
        float q1_ = D[(j_ - 3) & 15] * ew_[2];                                \
        float q2_ = D[(j_ - 4) & 15] * ew_[3];                                \
        float q3_ = D[(j_ - 5) & 15] * ew_[4];                                \
        q0_ = fmaf(D[(j_ - 6) & 15], ew_[5], q0_);                            \
        q1_ = fmaf(D[(j_ - 7) & 15], ew_[6], q1_);                            \
        q2_ = fmaf(D[(j_ - 8) & 15], ew_[7], q2_);                            \
        q3_ = fmaf(D[(j_ - 9) & 15], ew_[8], q3_);                            \
        q0_ = fmaf(D[(j_ - 10) & 15], ew_[9], q0_);                           \
        q1_ = fmaf(D[(j_ - 11) & 15], ew_[10], q1_);                          \
        q2_ = fmaf(D[(j_ - 12) & 15], ew_[11], q2_);                          \
        q3_ = fmaf(D[(j_ - 13) & 15], ew_[12], q3_);                          \
        q0_ = fmaf(D[(j_ - 14) & 15], ew_[13], q0_);                          \
        q1_ = fmaf(D[(j_ - 15) & 15], ew_[14], q1_);                          \
        q2_ = fmaf(D[(j_ - 16) & 15], ew_[15], q2_);                          \
        float p15_ = (q0_ + q1_) + (q2_ + q3_);                               \
        p15_ = (t == 0) ? 0.0f : p15_;     /* O-tag: span len 1 only */       \
        float Sv_ = fmaf(Dn_, ew_[0], p15_);                                  \
        if (IS_B0) {                                                          \
            float bt_ = etb0 * bem[j_];                                       \
            if (j_ > 0) bt_ = (t == 0) ? 0.0f : bt_;                          \
            Sv_ += bt_;                                                       \
        }                                                                     \
        Svp = Sv_;                                                            \
        Svk = Sv_;                                                            \
    }

// one 16-step block = 2 groups of 8. Invariant on entry: ring0 = s0..s0+7,
// gst = s0+8..s0+15 (raw). Exit: same with s0' = s0+16.
#define BLOCK16(B0, FIRST, SCALED)                                            \
    SCRF_STEP(0, B0, FIRST, SCALED)                                           \
    SCRF_STEP(1, B0, false, false)                                            \
    SCRF_STEP(2, B0, false, false)                                            \
    SCRF_STEP(3, B0, false, false)                                            \
    SCRF_STEP(4, B0, false, false)                                            \
    SCRF_STEP(5, B0, false, false)                                            \
    SCRF_STEP(6, B0, false, false)                                            \
    SCRF_STEP(7, B0, false, false)                                            \
    GROUPOPS(1, 16)                                                           \
    SCRF_STEP(8, B0, false, false)                                            \
    SCRF_STEP(9, B0, false, false)                                            \
    SCRF_STEP(10, B0, false, false)                                           \
    SCRF_STEP(11, B0, false, false)                                           \
    SCRF_STEP(12, B0, false, false)                                           \
    SCRF_STEP(13, B0, false, false)                                           \
    SCRF_STEP(14, B0, false, false)                                           \
    SCRF_STEP(15, B0, false, false)                                           \
    GROUPOPS(0, 24)

    // ---- prologue: steps s0..s0+7 -> ring0 (exp'd), stage s0+8..15 ----
    LOADG(0)
    {
#pragma unroll
        for (int l = 0; l < 16; ++l) {
            float4 e_;
            e_.x = __expf(w2 * gst[l].x);
            e_.y = __expf(w2 * gst[l].y);
            e_.z = __expf(w2 * gst[l].z);
            e_.w = __expf(w2 * gst[l].w);
            *(float4*)&ring0[l * 256 + lane * 4] = e_;
        }
    }
    LOADG(8)

    // ---- block 0 ----
    if (exact) {
        BLOCK16(true, true, false)
    } else {
        BLOCK16(false, false, false)
    }

    // ---- remaining blocks ----
    float m_pre = 0.0f;
    for (int b = 1; b < nb; ++b) {
        s0 += 16;
        if (b == preb) {   // capture m at global step c*K-1 (pre-rescale)
            float sv = Svk;
#pragma unroll
            for (int m = 1; m <= 16; m <<= 1) sv += __shfl_xor(sv, m);
            m_pre = mref + __logf(sv);
        }
        // re-anchor: divide history by max_t(Sv_last), recenter to e^-20
        float mx = Svk;
#pragma unroll
        for (int m = 1; m <= 16; m <<= 1)
            mx = fmaxf(mx, __shfl_xor(mx, m));
        inv = 2.0611536e-09f / mx;          // e^-20 / mx
        mref += __logf(mx) + 20.0f;
#pragma unroll
        for (int k = 0; k < 16; ++k) D[k] *= inv;

        BLOCK16(false, false, true)         // pending Svp's MVM gets *inv
    }
#undef BLOCK16
#undef SCRF_STEP
#undef GROUPOPS
#undef LOADG

    // ---- chunk outputs ----
    float se = Svk;
#pragma unroll
    for (int m = 1; m <= 16; m <<= 1) se += __shfl_xor(se, m);
    float m_end = mref + __logf(se);
    float contrib = (preb == 0) ? m_end : (m_end - m_pre);
    if (lane == 0) ws2[c] = contrib;
    if (c == C - 1) {
        float etb1 = __expf(w1 * tbound[TT + t]);
        float sc = Svk * etb1;
#pragma unroll
        for (int m = 1; m <= 16; m <<= 1) sc += __shfl_xor(sc, m);
        if (lane == 0) ws2[C] = __logf(sc) - __logf(se);
    }
}

// ---------------------------------------------------------------------------
// Ordered reduction of the C+1 chunk contributions.
// ---------------------------------------------------------------------------
__global__ void stitch_kernel(const float* __restrict__ ws2,
                              float* __restrict__ out, int n) {
    const int lane = (int)threadIdx.x;
    float v = 0.0f;
    for (int i = lane; i < n; i += 64) v += ws2[i];
#pragma unroll
    for (int m = 1; m <= 32; m <<= 1) v += __shfl_xor(v, m);
    if (lane == 0) out[0] = v;
}

// ---------------------------------------------------------------------------
// Fallback (S not a multiple of 64 / tiny ws): proven round-2 kernel.
// ---------------------------------------------------------------------------
__launch_bounds__(64, 1)
__global__ void semicrf_scan_fb_kernel(const float* __restrict__ src,
                                       const float* __restrict__ trans,
                                       const float* __restrict__ tbound,
                                       const float* __restrict__ w1p,
                                       const float* __restrict__ w2p,
                                       float* __restrict__ out, int S) {
    __shared__ float4 ldsS4[8];
    const int lane = threadIdx.x;
    const int t = lane & 31;
    const int h = lane >> 5;
    const float w1 = w1p[0];
    const float w2 = w2p[0];
    const unsigned toff = (unsigned)t * 4u;
    const unsigned planeB = (unsigned)S * 128u;
    const size_t planeE = (size_t)S * TT;

    float trx[16];
#pragma unroll
    for (int i = 0; i < 16; ++i)
        trx[i] = __expf(w1 * trans[t * TT + h * 16 + i]);

    float D[16];
#pragma unroll
    for (int k = 0; k < 16; ++k) D[k] = 0.0f;

    unsigned off[16];
#pragma unroll
    for (int k = 0; k < 16; ++k) {
        int l = (-1 - k) & 15;
        int c = 0 - l; if (c < 0) c = 0;
        off[k] = (unsigned)(l * S + c) * 128u + toff;
    }

    float ring[4][16];
#pragma unroll
    for (int st = 0; st < 4; ++st) {
#pragma unroll
        for (int k = 0; k < 16; ++k)
            ring[st][k] = *(const float*)((const char*)src + off[k]);
        const int qr = st & 15;
        unsigned c = (unsigned)((st + 1 <= S - 1) ? st + 1 : S - 1);
#pragma unroll
        for (int k = 0; k < 16; ++k)
            off[k] = (k == qr) ? (c * 128u + toff) : (off[k] + planeB);
    }

    float etb0 = __expf(w1 * tbound[t]);
    float bem[16];
#pragma unroll
    for (int j = 0; j < 16; ++j)
        bem[j] = __expf(w2 * src[(size_t)j * planeE + (size_t)t]);

    float mref = 0.0f;
    float Svk = 1.0f;

#define FB_STEP(J, S0V, IS_B0)                                                \
    {                                                                         \
        const int j_ = (J);                                                   \
        float ewv[16];                                                        \
        _Pragma("unroll")                                                     \
        for (int k = 0; k < 16; ++k)                                          \
            ewv[k] = __expf(w2 * ring[j_ & 3][k]);                            \
        float p0 = 0.f, p1 = 0.f, p2 = 0.f, p3 = 0.f;                         \
        _Pragma("unroll")                                                     \
        for (int k = 0; k < 16; k += 4) {                                     \
            p0 = fmaf(D[k + 0], ewv[k + 0], p0);                              \
            p1 = fmaf(D[k + 1], ewv[k + 1], p1);                              \
            p2 = fmaf(D[k + 2], ewv[k + 2], p2);                              \
            p3 = fmaf(D[k + 3], ewv[k + 3], p3);                              \
        }                                                                     \
        float part = (p0 + p1) + (p2 + p3);                                   \
        {                                                                     \
            const int kp = (j_ - 1) & 15;                                     \
            float alt = D[kp] * ewv[kp];                                      \
            part = (t == 0) ? alt : part;                                     \
        }                                                                     \
        _Pragma("unroll")                                                     \
        for (int k = 0; k < 16; ++k)                                          \
            ring[(j_ + 4) & 3][k] =                                           \
                *(const float*)((const char*)src + off[k]);                   \
        {                                                                     \
            const int qr = (j_ + 4) & 15;                                     \
            long T1 = (long)(S0V) + j_ + 4 + 1;                               \
            unsigned c_ = (unsigned)(T1 <= (long)(S - 1) ? T1 : (long)(S - 1)); \
            _Pragma("unroll")                                                 \
            for (int k = 0; k < 16; ++k)                                      \
                off[k] = (k == qr) ? (c_ * 128u + toff) : (off[k] + planeB);  \
        }                                                                     \
        float Sv = part + __shfl_xor(part, 32);                               \
        if (IS_B0) {                                                          \
            float bt = etb0 * bem[j_];                                        \
            if (j_ > 0) bt = (t == 0) ? 0.0f : bt;                            \
            Sv += bt;                                                         \
        }                                                                     \
        ((float*)ldsS4)[t] = Sv;                                              \
        __syncthreads();                                                      \
        float4 a0 = ldsS4[h * 4 + 0];                                         \
        float4 a1 = ldsS4[h * 4 + 1];                                         \
        float4 a2 = ldsS4[h * 4 + 2];                                         \
        float4 a3 = ldsS4[h * 4 + 3];                                         \
        float dn0 = fmaf(trx[0],  a0.x, fmaf(trx[1],  a0.y,                   \
                    fmaf(trx[2],  a0.z, trx[3]  * a0.w)));                    \
        float dn1 = fmaf(trx[4],  a1.x, fmaf(trx[5],  a1.y,                   \
                    fmaf(trx[6],  a1.z, trx[7]  * a1.w)));                    \
        float dn2 = fmaf(trx[8],  a2.x, fmaf(trx[9],  a2.y,                   \
                    fmaf(trx[10], a2.z, trx[11] * a2.w)));                    \
        float dn3 = fmaf(trx[12], a3.x, fmaf(trx[13], a3.y,                   \
                    fmaf(trx[14], a3.z, trx[15] * a3.w)));                    \
        D[j_] = (dn0 + dn1) + (dn2 + dn3);                                    \
        Svk = Sv;                                                             \
    }

#pragma unroll
    for (int j = 0; j < 16; ++j) {
        FB_STEP(j, 0L, true)
    }
    const int nblocks = S / 16;
    long s0 = 16;
    for (int b = 1; b < nblocks; ++b) {
        float mx = Svk;
#pragma unroll
        for (int m = 1; m <= 16; m <<= 1)
            mx = fmaxf(mx, __shfl_xor(mx, m));
        float invv = 2.0611536e-09f / mx;
        mref += __logf(mx) + 20.0f;
#pragma unroll
        for (int k = 0; k < 16; ++k) D[k] *= invv;
#pragma unroll
        for (int j = 0; j < 16; ++j) {
            FB_STEP(j, s0, false)
        }
        s0 += 16;
    }
#undef FB_STEP

    float etb1 = __expf(w1 * tbound[TT + t]);
    float val = Svk * etb1;
#pragma unroll
    for (int m = 1; m <= 16; m <<= 1) val += __shfl_xor(val, m);
    if (lane == 0) out[0] = mref + __logf(val);
}

// ---------------------------------------------------------------------------
extern "C" void kernel_launch(void* const* d_in, const int* in_sizes, int n_in,
                              void* d_out, int out_size, void* d_ws, size_t ws_size,
                              hipStream_t stream) {
    const float* feats = (const float*)d_in[0];   // [L=16, S, T=32]
    const float* trans = (const float*)d_in[1];   // [T, T]
    const float* tb    = (const float*)d_in[2];   // [2, T]
    const float* w1    = (const float*)d_in[3];
    const float* w2    = (const float*)d_in[4];
    float* out = (float*)d_out;

    const int n = in_sizes[0];            // L*S*T
    const int S = n / (LL * TT);

    // K=64 chunks (BURN=16): need S % 64 == 0.
    int C = 0;
    if ((S & 63) == 0 && S >= 192) C = S >> 6;
    const int swz = (C > 0 && (C & 7) == 0) ? 1 : 0;

    const size_t need = (size_t)(C + 2) * sizeof(float);
    if (C > 1 && ws_size >= need) {
        float* ws2 = (float*)d_ws;
        semicrf_rl_kernel<<<C, 64, 0, stream>>>(feats, trans, tb, w1, w2,
                                                ws2, S, C, swz);
        stitch_kernel<<<1, 64, 0, stream>>>(ws2, out, C + 1);
    } else {
        semicrf_scan_fb_kernel<<<1, 64, 0, stream>>>(feats, trans, tb, w1, w2, out, S);
    }
}

// Round 17
// 27.287 us; speedup vs baseline: 1.5857x; 1.3549x over previous
//
#include <hip/hip_runtime.h>

#define TT 32     // tags
#define LL 16     // max span length
#define BURN 8    // burn-in steps (BURN=16 absmax 0.0 => per-8-step
                  // contraction ~3e-3; 1023 seams -> total err <= ~3 << 2600)
#define KCH 32    // chunk payload length (steps); C = S/32 = 1024 = #SIMDs

// broadcast lane p's value to all lanes (VALU readlane, no LDS pipe)
#if __has_builtin(__builtin_amdgcn_readlane)
#define RLF(U, P) __uint_as_float(__builtin_amdgcn_readlane((U), (P)))
#else
#define RLF(U, P) __uint_as_float(__shfl((int)(U), (P)))
#endif

// ---------------------------------------------------------------------------
// Chunk-parallel scan, readlane-MVM, 8-step-half schedule (r14 + BURN=8).
// Chunk c: payload [c*32,(c+1)*32); window starts at gstart = max(0,c*32-8).
// c>0: 8-step burn-in from all-ones (phantom history slots suppressed by the
// e^{-4l} decay of old D terms; direction error ~3e-3/seam). c==0 exact.
// Per lane: tag t = lane&31 (halves duplicate), FULL 32-wide Trx row; after
// the dot every lane holds the complete S_t -> next step's MVM is 32x
// v_readlane + 32 fma, zero LDS on the recurrence. Emissions: 8-step groups
// staged float4/lane (1KB contiguous per plane), exp at stage time,
// double-buffered 16KB rings. Schedule = 8-step halves; ring parity
// alternates 0,1,0,1,0; rescale every 16 steps.
// ws2 telescoping identical to r14.
// ---------------------------------------------------------------------------
__launch_bounds__(64, 1)
__global__ void semicrf_rl_kernel(const float* __restrict__ feats,
                                  const float* __restrict__ trans,
                                  const float* __restrict__ tbound,
                                  const float* __restrict__ w1p,
                                  const float* __restrict__ w2p,
                                  float* __restrict__ ws2,
                                  int S, int C, int swz) {
    __shared__ __align__(16) float ring0[16 * 256];  // 16 planes x 8 steps x 32 t
    __shared__ __align__(16) float ring1[16 * 256];
    int c = (int)blockIdx.x;
    if (swz) c = (c & 7) * (C >> 3) + (c >> 3);      // XCD-contiguous chunks
    const int lane = (int)threadIdx.x;
    const int t = lane & 31;
    const float w1 = w1p[0];
    const float w2 = w2p[0];
    const int Sm1 = S - 1;

    int gstart = c * KCH - BURN;
    if (gstart < 0) gstart = 0;
    const bool exact = (gstart == 0);

    // full Trx row for this lane's tag (32 regs)
    float trx[32];
#pragma unroll
    for (int i = 0; i < 32; ++i)
        trx[i] = __expf(w1 * trans[t * TT + i]);
    float trxsum = 0.0f;
#pragma unroll
    for (int i = 0; i < 32; ++i) trxsum += trx[i];

    float D[16];
#pragma unroll
    for (int k = 0; k < 16; ++k) D[k] = exact ? 0.0f : trxsum;

    float etb0 = __expf(w1 * tbound[t]);
    float bem[16];
#pragma unroll
    for (int j = 0; j < 16; ++j) bem[j] = 0.0f;
    if (exact) {
#pragma unroll
        for (int j = 0; j < 16; ++j)                 // bemit[j] = feats[j][0][t]
            bem[j] = __expf(w2 * feats[(size_t)j * (size_t)S * 32u + (size_t)t]);
    }

    float mref = 0.0f, Svk = 1.0f, inv = 1.0f;
    float Svp = 1.0f;                // prev step's full S_t (ones init)
    const int s0 = gstart;
    float4 gst[16];                                  // staged raw: next 8 steps

// issue 16 float4 loads: 8-step strip (1KB contiguous) per plane at s0+OFF
#define LOADG(OFF)                                                            \
    {                                                                         \
        int gs_ = s0 + (OFF); if (gs_ > S - 8) gs_ = S - 8;                   \
        _Pragma("unroll")                                                     \
        for (int l = 0; l < 16; ++l)                                          \
            gst[l] = *(const float4*)(feats +                                 \
                ((size_t)l * (size_t)Sm1 + (size_t)gs_) * 32 + lane * 4);     \
    }

// exp the staged regs and write to ring buffer P
#define GROUPW(P)                                                             \
    {                                                                         \
        float* rw_ = (P) ? ring1 : ring0;                                     \
        _Pragma("unroll")                                                     \
        for (int l = 0; l < 16; ++l) {                                        \
            float4 e_;                                                        \
            e_.x = __expf(w2 * gst[l].x);                                     \
            e_.y = __expf(w2 * gst[l].y);                                     \
            e_.z = __expf(w2 * gst[l].z);                                     \
            e_.w = __expf(w2 * gst[l].w);                                     \
            *(float4*)&rw_[l * 256 + lane * 4] = e_;                          \
        }                                                                     \
    }

#define GROUPOPS(P, OFF) GROUPW(P) LOADG(OFF)

#define RESCALE()                                                             \
    {                                                                         \
        float mx_ = Svk;                                                      \
        _Pragma("unroll")                                                     \
        for (int m_ = 1; m_ <= 16; m_ <<= 1)                                  \
            mx_ = fmaxf(mx_, __shfl_xor(mx_, m_));                            \
        inv = 2.0611536e-09f / mx_;          /* e^-20 / mx */                 \
        mref += __logf(mx_) + 20.0f;                                          \
        _Pragma("unroll")                                                     \
        for (int k_ = 0; k_ < 16; ++k_) D[k_] *= inv;                         \
    }

#define SCRF_STEP(A, P, IS_B0, IS_FIRST, SCALED)                              \
    {                                                                         \
        const int a_ = (A);                                                   \
        const float* rb_ = (P) ? ring1 : ring0;                               \
        /* 16 pre-exp'd emissions (bank = t, broadcast across halves) */      \
        float ew_[16];                                                        \
        _Pragma("unroll")                                                     \
        for (int l = 0; l < 16; ++l)                                          \
            ew_[l] = rb_[l * 256 + (a_ & 7) * 32 + t];                        \
        /* MVM via 32x readlane of prev S (no LDS on the chain) */            \
        float Dn_;                                                            \
        if (IS_FIRST) {                                                       \
            Dn_ = 0.0f;                                                       \
        } else {                                                              \
            unsigned svu_ = __float_as_uint(Svp);                             \
            float ac_[4] = {0.f, 0.f, 0.f, 0.f};                              \
            _Pragma("unroll")                                                 \
            for (int p = 0; p < 32; ++p)                                      \
                ac_[p & 3] = fmaf(trx[p], RLF(svu_, p), ac_[p & 3]);          \
            float dh_ = (ac_[0] + ac_[1]) + (ac_[2] + ac_[3]);                \
            Dn_ = (SCALED) ? dh_ * inv : dh_;                                 \
            D[(a_ - 1) & 15] = Dn_;                                           \
        }                                                                     \
        float q0_ = D[(a_ - 2) & 15] * ew_[1];                                \
        float q1_ = D[(a_ - 3) & 15] * ew_[2];                                \
        float q2_ = D[(a_ - 4) & 15] * ew_[3];                                \
        float q3_ = D[(a_ - 5) & 15] * ew_[4];                                \
        q0_ = fmaf(D[(a_ - 6) & 15], ew_[5], q0_);                            \
        q1_ = fmaf(D[(a_ - 7) & 15], ew_[6], q1_);                            \
        q2_ = fmaf(D[(a_ - 8) & 15], ew_[7], q2_);                            \
        q3_ = fmaf(D[(a_ - 9) & 15], ew_[8], q3_);                            \
        q0_ = fmaf(D[(a_ - 10) & 15], ew_[9], q0_);                           \
        q1_ = fmaf(D[(a_ - 11) & 15], ew_[10], q1_);                          \
        q2_ = fmaf(D[(a_ - 12) & 15], ew_[11], q2_);                          \
        q3_ = fmaf(D[(a_ - 13) & 15], ew_[12], q3_);                          \
        q0_ = fmaf(D[(a_ - 14) & 15], ew_[13], q0_);                          \
        q1_ = fmaf(D[(a_ - 15) & 15], ew_[14], q1_);                          \
        q2_ = fmaf(D[(a_ - 16) & 15], ew_[15], q2_);                          \
        float p15_ = (q0_ + q1_) + (q2_ + q3_);                               \
        p15_ = (t == 0) ? 0.0f : p15_;     /* O-tag: span len 1 only */       \
        float Sv_ = fmaf(Dn_, ew_[0], p15_);                                  \
        if (IS_B0) {                                                          \
            float bt_ = etb0 * bem[a_];                                       \
            if (a_ > 0) bt_ = (t == 0) ? 0.0f : bt_;                          \
            Sv_ += bt_;                                                       \
        }                                                                     \
        Svp = Sv_;                                                            \
        Svk = Sv_;                                                            \
    }

// 8-step half: steps A0..A0+7 reading ring parity P
#define H8(A0, P, B0, FIRST, SCALED)                                          \
    SCRF_STEP((A0) + 0, P, B0, FIRST, SCALED)                                 \
    SCRF_STEP((A0) + 1, P, B0, false, false)                                  \
    SCRF_STEP((A0) + 2, P, B0, false, false)                                  \
    SCRF_STEP((A0) + 3, P, B0, false, false)                                  \
    SCRF_STEP((A0) + 4, P, B0, false, false)                                  \
    SCRF_STEP((A0) + 5, P, B0, false, false)                                  \
    SCRF_STEP((A0) + 6, P, B0, false, false)                                  \
    SCRF_STEP((A0) + 7, P, B0, false, false)

    // ---- prologue: G0 (steps 0-7) -> ring0 (exp'd), stage G1 (8-15) ----
    LOADG(0)
    GROUPW(0)
    LOADG(8)

    float m_pre = 0.0f, m_end;
    if (exact) {
        // 32-step exact window: 4 halves, boundary on steps 0-15
        H8(0, 0, true, true, false)          // steps 0-7
        GROUPOPS(1, 16)
        H8(8, 1, true, false, false)         // steps 8-15
        GROUPOPS(0, 24)
        RESCALE()
        H8(0, 0, false, false, true)         // steps 16-23 (scaled first MVM)
        GROUPW(1)                            // G3 (24-31) -> ring1, no load
        H8(8, 1, false, false, false)        // steps 24-31
    } else {
        // 40-step window: burn half + 4 payload halves
        H8(0, 0, false, false, false)        // burn: steps 0-7
        GROUPOPS(1, 16)
        {   // m_pre at local step 7 == global c*32-1 (pre-rescale)
            float sv = Svk;
#pragma unroll
            for (int m = 1; m <= 16; m <<= 1) sv += __shfl_xor(sv, m);
            m_pre = mref + __logf(sv);
        }
        RESCALE()
        H8(8, 1, false, false, true)         // payload steps 8-15
        GROUPOPS(0, 24)
        H8(0, 0, false, false, false)        // steps 16-23
        GROUPOPS(1, 32)
        RESCALE()
        H8(8, 1, false, false, true)         // steps 24-31
        GROUPW(0)                            // G4 (32-39) -> ring0, no load
        H8(0, 0, false, false, false)        // steps 32-39
    }
#undef H8
#undef SCRF_STEP
#undef RESCALE
#undef GROUPOPS
#undef GROUPW
#undef LOADG

    // ---- chunk outputs ----
    float se = Svk;
#pragma unroll
    for (int m = 1; m <= 16; m <<= 1) se += __shfl_xor(se, m);
    m_end = mref + __logf(se);
    float contrib = exact ? m_end : (m_end - m_pre);
    if (lane == 0) ws2[c] = contrib;
    if (c == C - 1) {
        float etb1 = __expf(w1 * tbound[TT + t]);
        float sc = Svk * etb1;
#pragma unroll
        for (int m = 1; m <= 16; m <<= 1) sc += __shfl_xor(sc, m);
        if (lane == 0) ws2[C] = __logf(sc) - __logf(se);
    }
}

// ---------------------------------------------------------------------------
// Ordered reduction of the C+1 chunk contributions.
// ---------------------------------------------------------------------------
__global__ void stitch_kernel(const float* __restrict__ ws2,
                              float* __restrict__ out, int n) {
    const int lane = (int)threadIdx.x;
    float v = 0.0f;
    for (int i = lane; i < n; i += 64) v += ws2[i];
#pragma unroll
    for (int m = 1; m <= 32; m <<= 1) v += __shfl_xor(v, m);
    if (lane == 0) out[0] = v;
}

// ---------------------------------------------------------------------------
// Fallback (S not a multiple of 32 / tiny ws): proven round-2 kernel.
// ---------------------------------------------------------------------------
__launch_bounds__(64, 1)
__global__ void semicrf_scan_fb_kernel(const float* __restrict__ src,
                                       const float* __restrict__ trans,
                                       const float* __restrict__ tbound,
                                       const float* __restrict__ w1p,
                                       const float* __restrict__ w2p,
                                       float* __restrict__ out, int S) {
    __shared__ float4 ldsS4[8];
    const int lane = threadIdx.x;
    const int t = lane & 31;
    const int h = lane >> 5;
    const float w1 = w1p[0];
    const float w2 = w2p[0];
    const unsigned toff = (unsigned)t * 4u;
    const unsigned planeB = (unsigned)S * 128u;
    const size_t planeE = (size_t)S * TT;

    float trx[16];
#pragma unroll
    for (int i = 0; i < 16; ++i)
        trx[i] = __expf(w1 * trans[t * TT + h * 16 + i]);

    float D[16];
#pragma unroll
    for (int k = 0; k < 16; ++k) D[k] = 0.0f;

    unsigned off[16];
#pragma unroll
    for (int k = 0; k < 16; ++k) {
        int l = (-1 - k) & 15;
        int c = 0 - l; if (c < 0) c = 0;
        off[k] = (unsigned)(l * S + c) * 128u + toff;
    }

    float ring[4][16];
#pragma unroll
    for (int st = 0; st < 4; ++st) {
#pragma unroll
        for (int k = 0; k < 16; ++k)
            ring[st][k] = *(const float*)((const char*)src + off[k]);
        const int qr = st & 15;
        unsigned c = (unsigned)((st + 1 <= S - 1) ? st + 1 : S - 1);
#pragma unroll
        for (int k = 0; k < 16; ++k)
            off[k] = (k == qr) ? (c * 128u + toff) : (off[k] + planeB);
    }

    float etb0 = __expf(w1 * tbound[t]);
    float bem[16];
#pragma unroll
    for (int j = 0; j < 16; ++j)
        bem[j] = __expf(w2 * src[(size_t)j * planeE + (size_t)t]);

    float mref = 0.0f;
    float Svk = 1.0f;

#define FB_STEP(J, S0V, IS_B0)                                                \
    {                                                                         \
        const int j_ = (J);                                                   \
        float ewv[16];                                                        \
        _Pragma("unroll")                                                     \
        for (int k = 0; k < 16; ++k)                                          \
            ewv[k] = __expf(w2 * ring[j_ & 3][k]);                            \
        float p0 = 0.f, p1 = 0.f, p2 = 0.f, p3 = 0.f;                         \
        _Pragma("unroll")                                                     \
        for (int k = 0; k < 16; k += 4) {                                     \
            p0 = fmaf(D[k + 0], ewv[k + 0], p0);                              \
            p1 = fmaf(D[k + 1], ewv[k + 1], p1);                              \
            p2 = fmaf(D[k + 2], ewv[k + 2], p2);                              \
            p3 = fmaf(D[k + 3], ewv[k + 3], p3);                              \
        }                                                                     \
        float part = (p0 + p1) + (p2 + p3);                                   \
        {                                                                     \
            const int kp = (j_ - 1) & 15;                                     \
            float alt = D[kp] * ewv[kp];                                      \
            part = (t == 0) ? alt : part;                                     \
        }                                                                     \
        _Pragma("unroll")                                                     \
        for (int k = 0; k < 16; ++k)                                          \
            ring[(j_ + 4) & 3][k] =                                           \
                *(const float*)((const char*)src + off[k]);                   \
        {                                                                     \
            const int qr = (j_ + 4) & 15;                                     \
            long T1 = (long)(S0V) + j_ + 4 + 1;                               \
            unsigned c_ = (unsigned)(T1 <= (long)(S - 1) ? T1 : (long)(S - 1)); \
            _Pragma("unroll")                                                 \
            for (int k = 0; k < 16; ++k)                                      \
                off[k] = (k == qr) ? (c_ * 128u + toff) : (off[k] + planeB);  \
        }                                                                     \
        float Sv = part + __shfl_xor(part, 32);                               \
        if (IS_B0) {                                                          \
            float bt = etb0 * bem[j_];                                        \
            if (j_ > 0) bt = (t == 0) ? 0.0f : bt;                            \
            Sv += bt;                                                         \
        }                                                                     \
        ((float*)ldsS4)[t] = Sv;                                              \
        __syncthreads();                                                      \
        float4 a0 = ldsS4[h * 4 + 0];                                         \
        float4 a1 = ldsS4[h * 4 + 1];                                         \
        float4 a2 = ldsS4[h * 4 + 2];                                         \
        float4 a3 = ldsS4[h * 4 + 3];                                         \
        float dn0 = fmaf(trx[0],  a0.x, fmaf(trx[1],  a0.y,                   \
                    fmaf(trx[2],  a0.z, trx[3]  * a0.w)));                    \
        float dn1 = fmaf(trx[4],  a1.x, fmaf(trx[5],  a1.y,                   \
                    fmaf(trx[6],  a1.z, trx[7]  * a1.w)));                    \
        float dn2 = fmaf(trx[8],  a2.x, fmaf(trx[9],  a2.y,                   \
                    fmaf(trx[10], a2.z, trx[11] * a2.w)));                    \
        float dn3 = fmaf(trx[12], a3.x, fmaf(trx[13], a3.y,                   \
                    fmaf(trx[14], a3.z, trx[15] * a3.w)));                    \
        D[j_] = (dn0 + dn1) + (dn2 + dn3);                                    \
        Svk = Sv;                                                             \
    }

#pragma unroll
    for (int j = 0; j < 16; ++j) {
        FB_STEP(j, 0L, true)
    }
    const int nblocks = S / 16;
    long s0 = 16;
    for (int b = 1; b < nblocks; ++b) {
        float mx = Svk;
#pragma unroll
        for (int m = 1; m <= 16; m <<= 1)
            mx = fmaxf(mx, __shfl_xor(mx, m));
        float invv = 2.0611536e-09f / mx;
        mref += __logf(mx) + 20.0f;
#pragma unroll
        for (int k = 0; k < 16; ++k) D[k] *= invv;
#pragma unroll
        for (int j = 0; j < 16; ++j) {
            FB_STEP(j, s0, false)
        }
        s0 += 16;
    }
#undef FB_STEP

    float etb1 = __expf(w1 * tbound[TT + t]);
    float val = Svk * etb1;
#pragma unroll
    for (int m = 1; m <= 16; m <<= 1) val += __shfl_xor(val, m);
    if (lane == 0) out[0] = mref + __logf(val);
}

// ---------------------------------------------------------------------------
extern "C" void kernel_launch(void* const* d_in, const int* in_sizes, int n_in,
                              void* d_out, int out_size, void* d_ws, size_t ws_size,
                              hipStream_t stream) {
    const float* feats = (const float*)d_in[0];   // [L=16, S, T=32]
    const float* trans = (const float*)d_in[1];   // [T, T]
    const float* tb    = (const float*)d_in[2];   // [2, T]
    const float* w1    = (const float*)d_in[3];
    const float* w2    = (const float*)d_in[4];
    float* out = (float*)d_out;

    const int n = in_sizes[0];            // L*S*T
    const int S = n / (LL * TT);

    // K=32 chunks (BURN=8): need S % 32 == 0.
    int C = 0;
    if ((S & 31) == 0 && S >= 96) C = S >> 5;
    const int swz = (C > 0 && (C & 7) == 0) ? 1 : 0;

    const size_t need = (size_t)(C + 2) * sizeof(float);
    if (C > 1 && ws_size >= need) {
        float* ws2 = (float*)d_ws;
        semicrf_rl_kernel<<<C, 64, 0, stream>>>(feats, trans, tb, w1, w2,
                                                ws2, S, C, swz);
        stitch_kernel<<<1, 64, 0, stream>>>(ws2, out, C + 1);
    } else {
        semicrf_scan_fb_kernel<<<1, 64, 0, stream>>>(feats, trans, tb, w1, w2, out, S);
    }
}